// Round 1
// baseline (133.141 us; speedup 1.0000x reference)
//
#include <hip/hip_runtime.h>
#include <math.h>

// ---------------------------------------------------------------------------
// OBB CIoU loss, N independent box pairs -> scalar mean.
// R12: PAIRS=2 -> PAIRS=1. Counter evidence: VALUBusy 41% with VALU-issue
// arithmetic matching exactly (67M issue-cycles = 28us = 0.41*69us), all
// other pipes idle, bank conflicts negligible (3K cyc/CU). Theory: the
// ~30KB fully-unrolled 2-pair body thrashes the shared L1 I-cache
// (correlated fetch stalls across all waves). PAIRS=1 halves the code
// footprint to ~15KB and doubles grid to 3907 blocks (past the 2048
// full-residency count -> better balance/tail). pair_loss untouched.
// Carried from R9/R11: float2 packed math, atan-identity v-term, frcp
// divides, bf16 payload slab + packed-uint key Batcher sort + LDS gather,
// 16-vertex compacted candidates, diamond pseudo-angle, native sin/cos,
// exact-reference semantics.
// ---------------------------------------------------------------------------

#define BLOCK 256
#define NV 16
#define LDS_STRIDE 17   // 16 dword slots + 1 pad (odd stride -> free aliasing)

typedef float v2f __attribute__((ext_vector_type(2)));

// --- compile-time Batcher odd-even mergesort network for n=16 ---
struct CEList {
    int n;
    unsigned char lo[128];
    unsigned char hi[128];
};

constexpr CEList make_ces16() {
    CEList L{};
    L.n = 0;
    for (int p = 1; p < NV; p <<= 1)
        for (int k = p; k >= 1; k >>= 1)
            for (int j = k % p; j + k < NV; j += 2 * k)
                for (int i = 0; i < k; i++) {
                    int lo = i + j, hi = i + j + k;
                    if (hi < NV && (lo / (2 * p)) == (hi / (2 * p))) {
                        L.lo[L.n] = (unsigned char)lo;
                        L.hi[L.n] = (unsigned char)hi;
                        L.n++;
                    }
                }
    return L;
}

constexpr CEList CES = make_ces16();

__device__ __forceinline__ float frcp(float x) {
    return __builtin_amdgcn_rcpf(x);
}

__device__ __forceinline__ v2f splat2(float x) {
    v2f r; r.x = x; r.y = x; return r;
}

__device__ __forceinline__ float hadd2(v2f v) { return v.x + v.y; }

// Diamond pseudo-angle, no wrap: range [0,4), a cyclic shift of atan2 order.
// Cyclic shoelace is shift-invariant. All values nonneg -> uint-monotone.
__device__ __forceinline__ float angle_key(float x, float y) {
    float ax = fabsf(x), ay = fabsf(y);
    float den = ax + ay;
    float r = x * frcp(den);
    r = (den > 0.f) ? r : 0.f;
    return (y >= 0.f) ? (1.f - r) : (3.f + r);
}

// Pack two floats to bf16x2 with round-to-nearest (payload only; keys exact).
__device__ __forceinline__ unsigned int pack_bf2(float x, float y) {
    unsigned int bx = __float_as_uint(x) + 0x8000u;
    unsigned int by = __float_as_uint(y) + 0x8000u;
    return (by & 0xFFFF0000u) | (bx >> 16);
}

// atan(z) for z in [0,1]: degree-11 odd minimax, max err ~1.5e-5 rad.
__device__ __forceinline__ float atan01(float z) {
    float z2 = z * z;
    float p = -0.01172120f;
    p = p * z2 + 0.05265332f;
    p = p * z2 - 0.11643287f;
    p = p * z2 + 0.19354346f;
    p = p * z2 - 0.33262347f;
    p = p * z2 + 0.99997726f;
    return z * p;
}

__device__ __forceinline__ float pair_loss(const float* __restrict__ p,
                                           const float* __restrict__ t,
                                           float wv,
                                           unsigned int* __restrict__ myb)
{
    const float EPSf  = 1e-8f;   // segment-intersection eps (reference EPS)
    const float TOLf  = 1e-6f;   // box_in_box tol
    const float MEPS  = 1e-6f;   // MODE_EPS
    const float PIf   = 3.14159265358979323846f;

    float pcx = p[0], pcy = p[1], pw = p[2], ph = p[3], pa = p[4];
    float tcx = t[0], tcy = t[1], tw = t[2], th = t[3], ta = t[4];

    // ---- corners (packed) ---- (|angles| bounded: native sin/cos OK)
    float ca = __cosf(pa), sa = __sinf(pa);
    float cb = __cosf(ta), sb = __sinf(ta);
    v2f C1[4], C2[4];
    {
        const float xs[4] = { 0.5f, -0.5f, -0.5f, 0.5f };
        const float ys[4] = { -0.5f, -0.5f, 0.5f, 0.5f };
        v2f R1x = { ca, sa },  R1y = { -sa, cb };  // placeholder fixed below
        R1y.x = -sa; R1y.y = ca;
        v2f R2x = { cb, sb },  R2y = { -sb, cb };
        R2y.x = -sb; R2y.y = cb;
        v2f CT1 = { pcx, pcy }, CT2 = { tcx, tcy };
        #pragma unroll
        for (int k = 0; k < 4; k++) {
            float x4 = xs[k] * pw, y4 = ys[k] * ph;
            C1[k] = splat2(x4) * R1x + splat2(y4) * R1y + CT1;
            float x4b = xs[k] * tw, y4b = ys[k] * th;
            C2[k] = splat2(x4b) * R2x + splat2(y4b) * R2y + CT2;
        }
    }

    // ---- 16 candidate vertices + validity masks ----
    v2f  V[NV];
    bool msk[NV];

    // corners1 inside box2  (verts 0..3)
    {
        v2f A  = C2[0];
        v2f AB = C2[1] - A, AD = C2[3] - A;
        float rab = frcp(hadd2(AB * AB));
        float rad = frcp(hadd2(AD * AD));
        #pragma unroll
        for (int k = 0; k < 4; k++) {
            v2f AM = C1[k] - A;
            float pab = hadd2(AB * AM) * rab;
            float pad = hadd2(AD * AM) * rad;
            msk[k] = (pab > -TOLf) && (pab < 1.f + TOLf) &&
                     (pad > -TOLf) && (pad < 1.f + TOLf);
            V[k] = C1[k];
        }
    }
    // corners2 inside box1  (verts 4..7)
    {
        v2f A  = C1[0];
        v2f AB = C1[1] - A, AD = C1[3] - A;
        float rab = frcp(hadd2(AB * AB));
        float rad = frcp(hadd2(AD * AD));
        #pragma unroll
        for (int k = 0; k < 4; k++) {
            v2f AM = C2[k] - A;
            float pab = hadd2(AB * AM) * rab;
            float pad = hadd2(AD * AM) * rad;
            msk[4 + k] = (pab > -TOLf) && (pab < 1.f + TOLf) &&
                         (pad > -TOLf) && (pad < 1.f + TOLf);
            V[4 + k] = C2[k];
        }
    }
    // edge x edge intersections, compacted 4 -> 2 per box1 edge
    #pragma unroll
    for (int e1 = 0; e1 < 4; e1++) {
        v2f P1 = C1[e1];
        v2f E  = C1[(e1 + 1) & 3] - P1;
        v2f  Q[4];
        bool qm[4];
        #pragma unroll
        for (int e2 = 0; e2 < 4; e2++) {
            v2f P3 = C2[e2];
            v2f F  = C2[(e2 + 1) & 3] - P3;
            float num  = F.y * E.x - F.x * E.y;
            float rnum = frcp(num + EPSf);
            v2f D = P1 - P3;
            float den_t = F.x * D.y - F.y * D.x;
            float den_u = E.x * D.y - E.y * D.x;
            float tt = den_t * rnum;
            float uu = -den_u * rnum;
            qm[e2] = (num != 0.f) && (tt > 0.f) && (tt < 1.f)
                                  && (uu > 0.f) && (uu < 1.f);
            Q[e2] = splat2(tt) * E + P1;
        }
        bool mfL = qm[0] || qm[1];
        v2f  fL  = qm[0] ? Q[0] : Q[1];
        bool msL = qm[0] && qm[1];
        bool mfR = qm[2] || qm[3];
        v2f  fR  = qm[2] ? Q[2] : Q[3];
        bool msR = qm[2] && qm[3];
        int s0 = 8 + 2 * e1, s1 = s0 + 1;
        V[s0]   = mfL ? fL : fR;
        msk[s0] = mfL || mfR;
        v2f  t2 = msL ? Q[1] : fR;
        V[s1]   = mfL ? t2 : Q[3];
        msk[s1] = msL || (mfL && mfR) || msR;
    }

    // ---- centroid of valid verts ----
    v2f s2 = { 0.f, 0.f };
    float cnt = 0.f;
    const v2f Z2 = { 0.f, 0.f };
    #pragma unroll
    for (int k = 0; k < NV; k++) {
        s2  += msk[k] ? V[k] : Z2;
        cnt += msk[k] ? 1.f : 0.f;
    }
    float rden = frcp(fmaxf(cnt, 1.f));
    v2f cen = s2 * splat2(rden);

    // ---- relative coords -> LDS scatter (bf16x2) + packed key (key|slot) ----
    unsigned int ku[NV];
    #pragma unroll
    for (int k = 0; k < NV; k++) {
        v2f R = V[k] - cen;
        myb[k] = pack_bf2(R.x, R.y);
        float a = msk[k] ? angle_key(R.x, R.y) : 1e7f;  // key from FULL floats
        ku[k] = (__float_as_uint(a) & 0xFFFFFFF0u) | (unsigned int)k;
    }

    // ---- sort 16 packed keys (Batcher network, 2 VALU per CE) ----
    #pragma unroll
    for (int c = 0; c < CES.n; c++) {
        const int lo = CES.lo[c], hi = CES.hi[c];
        unsigned int a = ku[lo], b = ku[hi];
        ku[lo] = a < b ? a : b;
        ku[hi] = a < b ? b : a;
    }

    // ---- gather payload by sorted index; shoelace ----
    const unsigned int VALID_LIM = 0x49742400u;  // bits of 1e6f
    float gx[NV], gy[NV];
    bool  gv[NV];
    #pragma unroll
    for (int k = 0; k < NV; k++) {
        unsigned int pk = myb[ku[k] & 15u];
        gx[k] = __uint_as_float(pk << 16);
        gy[k] = __uint_as_float(pk & 0xFFFF0000u);
        gv[k] = ku[k] < VALID_LIM;
    }
    float fx = gx[0], fy = gy[0];
    float cross = 0.f;
    #pragma unroll
    for (int k = 0; k < NV; k++) {
        int kn = (k + 1) % NV;           // constant after unroll
        float axv = gv[k]  ? gx[k]  : fx, ayv = gv[k]  ? gy[k]  : fy;
        float bxv = gv[kn] ? gx[kn] : fx, byv = gv[kn] ? gy[kn] : fy;
        cross += axv * byv - ayv * bxv;
    }
    float inter = fabsf(cross) * 0.5f;

    // ---- CIoU ----
    float area1 = pw * ph, area2 = tw * th;
    float iou = inter * frcp(area1 + area2 - inter);
    iou = fminf(fmaxf(iou, 0.f), 1.f);

    float cA = fabsf(ca), sA = fabsf(sa);
    float cB = fabsf(cb), sB = fabsf(sb);
    float dw1 = (pw * cA + ph * sA) * 0.5f, dh1 = (pw * sA + ph * cA) * 0.5f;
    float dw2 = (tw * cB + th * sB) * 0.5f, dh2 = (tw * sB + th * cB) * 0.5f;
    float hp0 = pcx - dw1, hp1 = pcy - dh1, hp2 = pcx + dw1, hp3 = pcy + dh1;
    float ht0 = tcx - dw2, ht1 = tcy - dh2, ht2 = tcx + dw2, ht3 = tcy + dh2;

    float enw = fmaxf(fmaxf(hp2, ht2) - fminf(hp0, ht0), 0.f);
    float enh = fmaxf(fmaxf(hp3, ht3) - fminf(hp1, ht1), 0.f);
    float c2v = enw * enw + enh * enh + MEPS;
    float rho2 = (tcx - pcx) * (tcx - pcx) + (tcy - pcy) * (tcy - pcy);

    // v-term: atan(r1) - atan(r2) = atan((r1-r2)/(1+r1*r2)), exact for
    // r1*r2 > 0 (both aspect ratios positive). dv is squared -> sign-free.
    float factor = 4.f / (PIf * PIf);
    float r1 = tw * frcp(th + MEPS);
    float r2 = pw * frcp(ph + MEPS);
    float xd = (r1 - r2) * frcp(1.f + r1 * r2);
    float axd = fabsf(xd);
    bool  big = axd > 1.f;
    float z   = big ? frcp(axd) : axd;
    float at  = atan01(z);
    float dv  = big ? ((0.5f * PIf) - at) : at;   // |atan(xd)|
    float v_ = factor * dv * dv;
    float alpha = (iou > 0.5f) ? v_ * frcp(1.f - iou + v_ + MEPS) : 0.f;

    float rhoterm = fminf(fmaxf(rho2 * frcp(c2v), 0.f), 1.f);
    float ciou = iou - (rhoterm + alpha * v_);
    return (1.f - ciou) * wv;
}

__global__ __launch_bounds__(BLOCK)
void obb_ciou_kernel(const float* __restrict__ pred,
                     const float* __restrict__ tgt,
                     const float* __restrict__ wgt,
                     float* __restrict__ out,
                     int N, float invN)
{
    __shared__ unsigned int slab[BLOCK * LDS_STRIDE];
    unsigned int* myb = slab + (int)threadIdx.x * LDS_STRIDE;

    int i = blockIdx.x * BLOCK + (int)threadIdx.x;
    float loss = 0.f;
    if (i < N)
        loss = pair_loss(pred + (size_t)i * 5, tgt + (size_t)i * 5,
                         wgt[i], myb);

    // ---- reduction: wave shuffle -> LDS -> one atomic per block ----
    #pragma unroll
    for (int off = 32; off > 0; off >>= 1)
        loss += __shfl_down(loss, off, 64);

    __shared__ float red[BLOCK / 64];
    int wave = threadIdx.x >> 6;
    int lane = threadIdx.x & 63;
    if (lane == 0) red[wave] = loss;
    __syncthreads();
    if (threadIdx.x == 0) {
        float s = 0.f;
        #pragma unroll
        for (int w = 0; w < BLOCK / 64; w++) s += red[w];
        atomicAdd(out, s * invN);
    }
}

extern "C" void kernel_launch(void* const* d_in, const int* in_sizes, int n_in,
                              void* d_out, int out_size, void* d_ws, size_t ws_size,
                              hipStream_t stream) {
    const float* pred = (const float*)d_in[0];
    const float* tgt  = (const float*)d_in[1];
    const float* wgt  = (const float*)d_in[2];
    float* out = (float*)d_out;
    int N = in_sizes[2];  // weight element count == N boxes

    hipMemsetAsync(out, 0, sizeof(float) * (size_t)out_size, stream);

    int grid = (N + BLOCK - 1) / BLOCK;
    obb_ciou_kernel<<<grid, BLOCK, 0, stream>>>(pred, tgt, wgt, out, N,
                                                1.f / (float)N);
}

// Round 3
// 129.809 us; speedup vs baseline: 1.0257x; 1.0257x over previous
//
#include <hip/hip_runtime.h>
#include <math.h>

// ---------------------------------------------------------------------------
// OBB CIoU loss, N independent box pairs -> scalar mean.
// R14: KEY INSIGHT from R13's failure: the reference's box_intersection has a
// sign quirk -- its u = -den_u/(num+EPS) is the NEGATIVE of the true edge2
// parameter, so it accepts crossings of box1 edges with the BACKWARD
// extensions (u_true in (-1,0)) of box2 edges. The "intersection polygon" is
// therefore NOT the true intersection; any closed-form true-area shortcut
// (R13's Green's theorem) is structurally wrong (absmax 0.55). R11 passed
// bit-exactly because it replicated the quirk.
// R14 keeps R11's quirky semantics + sort/shoelace back half verbatim, but
// generates the 16 candidate vertices in box1's axis frame:
//   - box1 corners are (+-hw1, +-hh1) constants
//   - c2_in_1 mask == |Cx|<hw1*(1+2tol) && |Cy|<hh1*(1+2tol)  (exact rewrite
//     of reference p_ab/p_ad window); c1_in_2 via box2 slab coords
//   - each edge crossing: u=(c-Sy)*rDy; x=fma(u,Dx,Sx);
//     accept (u>-1 && u<0 && |x|<hw1)   [u-window = frame-invariant image of
//     the reference's flipped-u mask; |x|<hw1 == t in (0,1); inf/NaN from
//     parallel edges auto-reject, matching num==0]
// Rotation shifts all angles uniformly -> diamond-key order is a cyclic
// shift -> cyclic shoelace invariant (same argument as R6).
// Carried: bf16 payload slab + packed-uint key Batcher sort + LDS gather,
// diamond pseudo-angle, native sin/cos, atan-identity v-term, frcp divides.
// ---------------------------------------------------------------------------

#define BLOCK 256
#define NV 16
#define LDS_STRIDE 17   // 16 dword slots + 1 pad (odd stride -> free aliasing)

typedef float v2f __attribute__((ext_vector_type(2)));

// --- compile-time Batcher odd-even mergesort network for n=16 ---
struct CEList {
    int n;
    unsigned char lo[128];
    unsigned char hi[128];
};

constexpr CEList make_ces16() {
    CEList L{};
    L.n = 0;
    for (int p = 1; p < NV; p <<= 1)
        for (int k = p; k >= 1; k >>= 1)
            for (int j = k % p; j + k < NV; j += 2 * k)
                for (int i = 0; i < k; i++) {
                    int lo = i + j, hi = i + j + k;
                    if (hi < NV && (lo / (2 * p)) == (hi / (2 * p))) {
                        L.lo[L.n] = (unsigned char)lo;
                        L.hi[L.n] = (unsigned char)hi;
                        L.n++;
                    }
                }
    return L;
}

constexpr CEList CES = make_ces16();

__device__ __forceinline__ float frcp(float x) {
    return __builtin_amdgcn_rcpf(x);
}

// Diamond pseudo-angle, no wrap: range [0,4), a cyclic shift of atan2 order.
__device__ __forceinline__ float angle_key(float x, float y) {
    float ax = fabsf(x), ay = fabsf(y);
    float den = ax + ay;
    float r = x * frcp(den);
    r = (den > 0.f) ? r : 0.f;
    return (y >= 0.f) ? (1.f - r) : (3.f + r);
}

// Pack two floats to bf16x2 with round-to-nearest (payload only; keys exact).
__device__ __forceinline__ unsigned int pack_bf2(float x, float y) {
    unsigned int bx = __float_as_uint(x) + 0x8000u;
    unsigned int by = __float_as_uint(y) + 0x8000u;
    return (by & 0xFFFF0000u) | (bx >> 16);
}

// atan(z) for z in [0,1]: degree-11 odd minimax, max err ~1.5e-5 rad.
__device__ __forceinline__ float atan01(float z) {
    float z2 = z * z;
    float p = -0.01172120f;
    p = p * z2 + 0.05265332f;
    p = p * z2 - 0.11643287f;
    p = p * z2 + 0.19354346f;
    p = p * z2 - 0.33262347f;
    p = p * z2 + 0.99997726f;
    return z * p;
}

__device__ __forceinline__ float pair_loss(const float* __restrict__ p,
                                           const float* __restrict__ t,
                                           float wv,
                                           unsigned int* __restrict__ myb)
{
    const float MEPS = 1e-6f;           // MODE_EPS
    const float PIf  = 3.14159265358979323846f;
    const float TOLm = 1.f + 2e-6f;     // (1 + 2*tol) slab half-width scale

    float pcx = p[0], pcy = p[1], pw = p[2], ph = p[3], pa = p[4];
    float tcx = t[0], tcy = t[1], tw = t[2], th = t[3], ta = t[4];

    // |angles| bounded -> native sin/cos OK
    float ca = __cosf(pa), sa = __sinf(pa);
    float cb = __cosf(ta), sb = __sinf(ta);

    float hw1 = 0.5f * pw, hh1 = 0.5f * ph;
    float hw2 = 0.5f * tw, hh2 = 0.5f * th;

    // ---- box2 in box1's axis frame ----
    float ddx = tcx - pcx, ddy = tcy - pcy;
    float c2x = ddx * ca + ddy * sa;
    float c2y = ddy * ca - ddx * sa;
    float cd  = cb * ca + sb * sa;      // cos(ta - pa)
    float sd  = sb * ca - cb * sa;      // sin(ta - pa)

    // box2 half-axes: A = hw2*(cd,sd), B = hh2*(-sd,cd)
    // reference corner ring: C0 = q+A-B, C1 = q-A-B, C2 = q-A+B, C3 = q+A+B
    float Axv = hw2 * cd,  Ayv = hw2 * sd;
    float Bxv = -hh2 * sd, Byv = hh2 * cd;
    float qpAx = c2x + Axv, qpAy = c2y + Ayv;
    float qmAx = c2x - Axv, qmAy = c2y - Ayv;
    float C0x = qpAx - Bxv, C0y = qpAy - Byv;
    float C1x = qmAx - Bxv, C1y = qmAy - Byv;
    float C2x = qmAx + Bxv, C2y = qmAy + Byv;
    float C3x = qpAx + Bxv, C3y = qpAy + Byv;

    v2f  V[NV];
    bool msk[NV];

    // ---- corners1 (= (+-hw1,+-hh1), ring order) inside box2 -> slots 0..3
    // reference p_ab/p_ad window == |du|<hw2*(1+2tol) && |dv|<hh2*(1+2tol),
    // du = dot(K - q, (cd,sd)), dv = dot(K - q, (-sd,cd)).
    {
        float exl = -hw1 - c2x, exh = hw1 - c2x;
        float eyl = -hh1 - c2y, eyh = hh1 - c2y;
        float lw2 = hw2 * TOLm, lh2 = hh2 * TOLm;
        float du, dv;
        du = exh * cd + eyl * sd; dv = eyl * cd - exh * sd;   // K0=( hw1,-hh1)
        msk[0] = (fabsf(du) < lw2) && (fabsf(dv) < lh2);
        V[0] = (v2f){ hw1, -hh1 };
        du = exl * cd + eyl * sd; dv = eyl * cd - exl * sd;   // K1=(-hw1,-hh1)
        msk[1] = (fabsf(du) < lw2) && (fabsf(dv) < lh2);
        V[1] = (v2f){ -hw1, -hh1 };
        du = exl * cd + eyh * sd; dv = eyh * cd - exl * sd;   // K2=(-hw1, hh1)
        msk[2] = (fabsf(du) < lw2) && (fabsf(dv) < lh2);
        V[2] = (v2f){ -hw1, hh1 };
        du = exh * cd + eyh * sd; dv = eyh * cd - exh * sd;   // K3=( hw1, hh1)
        msk[3] = (fabsf(du) < lw2) && (fabsf(dv) < lh2);
        V[3] = (v2f){ hw1, hh1 };
    }

    // ---- corners2 inside box1 (axis-aligned slab) -> slots 4..7
    {
        float lw1 = hw1 * TOLm, lh1 = hh1 * TOLm;
        msk[4] = (fabsf(C0x) < lw1) && (fabsf(C0y) < lh1); V[4] = (v2f){C0x, C0y};
        msk[5] = (fabsf(C1x) < lw1) && (fabsf(C1y) < lh1); V[5] = (v2f){C1x, C1y};
        msk[6] = (fabsf(C2x) < lw1) && (fabsf(C2y) < lh1); V[6] = (v2f){C2x, C2y};
        msk[7] = (fabsf(C3x) < lw1) && (fabsf(C3y) < lh1); V[7] = (v2f){C3x, C3y};
    }

    // ---- quirky edge crossings -> slots 8..15 (2 per box1 edge) ----
    // box2 edge j: start S_j = C_j, dir D_j: D0=-2A, D1=+2B, D2=+2A, D3=-2B
    {
        float twcd = Axv + Axv, twsd = Ayv + Ayv;          // 2A
        float thsd = -(Bxv + Bxv), thcd = Byv + Byv;       // 2B = (-thsd, thcd)
        float rax = frcp(twcd), ray = frcp(twsd);
        float rbx = frcp(thsd), rby = frcp(thcd);

        float Sx[4]  = { C0x, C1x, C2x, C3x };
        float Sy[4]  = { C0y, C1y, C2y, C3y };
        float Dxe[4] = { -twcd, -thsd, twcd, thsd };
        float Dye[4] = { -twsd, thcd, twsd, -thcd };
        float iDx[4] = { -rax, -rbx, rax, rbx };
        float iDy[4] = { -ray, rby, ray, -rby };

        #pragma unroll
        for (int e1 = 0; e1 < 4; e1++) {
            // box1 ring: e0 bottom(y=-hh1), e1 left(x=-hw1),
            //            e2 top(y=+hh1),   e3 right(x=+hw1)
            const bool horiz = (e1 == 0) || (e1 == 2);
            const float cc   = (e1 == 0) ? -hh1 : (e1 == 1) ? -hw1
                             : (e1 == 2) ?  hh1 :  hw1;
            const float lim  = horiz ? hw1 : hh1;
            float q[4]; bool qm[4];
            #pragma unroll
            for (int j = 0; j < 4; j++) {
                float u = horiz ? (cc - Sy[j]) * iDy[j]
                                : (cc - Sx[j]) * iDx[j];
                float w = horiz ? fmaf(u, Dxe[j], Sx[j])
                                : fmaf(u, Dye[j], Sy[j]);
                // u in (-1,0): frame-exact image of reference's flipped-u
                // mask; |w|<lim == t in (0,1); parallel -> inf/NaN -> reject.
                qm[j] = (u > -1.f) && (u < 0.f) && (fabsf(w) < lim);
                q[j] = w;
            }
            bool mfL = qm[0] || qm[1];
            float fL = qm[0] ? q[0] : q[1];
            bool msL = qm[0] && qm[1];
            bool mfR = qm[2] || qm[3];
            float fR = qm[2] ? q[2] : q[3];
            bool msR = qm[2] && qm[3];
            int s0 = 8 + 2 * e1, s1 = s0 + 1;
            float w0 = mfL ? fL : fR;
            msk[s0]  = mfL || mfR;
            float t2v = msL ? q[1] : fR;
            float w1 = mfL ? t2v : q[3];
            msk[s1]  = msL || (mfL && mfR) || msR;
            V[s0] = horiz ? (v2f){ w0, cc } : (v2f){ cc, w0 };
            V[s1] = horiz ? (v2f){ w1, cc } : (v2f){ cc, w1 };
        }
    }

    // ---- centroid of valid verts ----
    v2f s2 = { 0.f, 0.f };
    float cnt = 0.f;
    const v2f Z2 = { 0.f, 0.f };
    #pragma unroll
    for (int k = 0; k < NV; k++) {
        s2  += msk[k] ? V[k] : Z2;
        cnt += msk[k] ? 1.f : 0.f;
    }
    float rden = frcp(fmaxf(cnt, 1.f));
    v2f cen = s2 * (v2f){ rden, rden };

    // ---- relative coords -> LDS scatter (bf16x2) + packed key (key|slot) ----
    unsigned int ku[NV];
    #pragma unroll
    for (int k = 0; k < NV; k++) {
        v2f R = V[k] - cen;
        myb[k] = pack_bf2(R.x, R.y);
        float a = msk[k] ? angle_key(R.x, R.y) : 1e7f;  // key from FULL floats
        ku[k] = (__float_as_uint(a) & 0xFFFFFFF0u) | (unsigned int)k;
    }

    // ---- sort 16 packed keys (Batcher network, 2 VALU per CE) ----
    #pragma unroll
    for (int c = 0; c < CES.n; c++) {
        const int lo = CES.lo[c], hi = CES.hi[c];
        unsigned int a = ku[lo], b = ku[hi];
        ku[lo] = a < b ? a : b;
        ku[hi] = a < b ? b : a;
    }

    // ---- gather payload by sorted index; shoelace ----
    const unsigned int VALID_LIM = 0x49742400u;  // bits of 1e6f
    float gx[NV], gy[NV];
    bool  gv[NV];
    #pragma unroll
    for (int k = 0; k < NV; k++) {
        unsigned int pk = myb[ku[k] & 15u];
        gx[k] = __uint_as_float(pk << 16);
        gy[k] = __uint_as_float(pk & 0xFFFF0000u);
        gv[k] = ku[k] < VALID_LIM;
    }
    float fx = gx[0], fy = gy[0];
    float cross = 0.f;
    #pragma unroll
    for (int k = 0; k < NV; k++) {
        int kn = (k + 1) % NV;           // constant after unroll
        float axv = gv[k]  ? gx[k]  : fx, ayv = gv[k]  ? gy[k]  : fy;
        float bxv = gv[kn] ? gx[kn] : fx, byv = gv[kn] ? gy[kn] : fy;
        cross += axv * byv - ayv * bxv;
    }
    float inter = fabsf(cross) * 0.5f;

    // ---- CIoU ----
    float area1 = pw * ph, area2 = tw * th;
    float iou = inter * frcp(area1 + area2 - inter);
    iou = fminf(fmaxf(iou, 0.f), 1.f);

    float cA = fabsf(ca), sA = fabsf(sa);
    float cB = fabsf(cb), sB = fabsf(sb);
    float dw1 = (pw * cA + ph * sA) * 0.5f, dh1 = (pw * sA + ph * cA) * 0.5f;
    float dw2 = (tw * cB + th * sB) * 0.5f, dh2 = (tw * sB + th * cB) * 0.5f;
    float hp0 = pcx - dw1, hp1 = pcy - dh1, hp2 = pcx + dw1, hp3 = pcy + dh1;
    float ht0 = tcx - dw2, ht1 = tcy - dh2, ht2 = tcx + dw2, ht3 = tcy + dh2;

    float enw = fmaxf(fmaxf(hp2, ht2) - fminf(hp0, ht0), 0.f);
    float enh = fmaxf(fmaxf(hp3, ht3) - fminf(hp1, ht1), 0.f);
    float c2v = enw * enw + enh * enh + MEPS;
    float rho2 = (tcx - pcx) * (tcx - pcx) + (tcy - pcy) * (tcy - pcy);

    // v-term: atan(r1) - atan(r2) = atan((r1-r2)/(1+r1*r2)), exact for
    // r1*r2 > 0 (both aspect ratios positive). dv is squared -> sign-free.
    float factor = 4.f / (PIf * PIf);
    float r1 = tw * frcp(th + MEPS);
    float r2 = pw * frcp(ph + MEPS);
    float xd = (r1 - r2) * frcp(1.f + r1 * r2);
    float axd = fabsf(xd);
    bool  big = axd > 1.f;
    float z   = big ? frcp(axd) : axd;
    float at  = atan01(z);
    float dv  = big ? ((0.5f * PIf) - at) : at;   // |atan(xd)|
    float v_ = factor * dv * dv;
    float alpha = (iou > 0.5f) ? v_ * frcp(1.f - iou + v_ + MEPS) : 0.f;

    float rhoterm = fminf(fmaxf(rho2 * frcp(c2v), 0.f), 1.f);
    float ciou = iou - (rhoterm + alpha * v_);
    return (1.f - ciou) * wv;
}

__global__ __launch_bounds__(BLOCK)
void obb_ciou_kernel(const float* __restrict__ pred,
                     const float* __restrict__ tgt,
                     const float* __restrict__ wgt,
                     float* __restrict__ out,
                     int N, float invN)
{
    __shared__ unsigned int slab[BLOCK * LDS_STRIDE];
    unsigned int* myb = slab + (int)threadIdx.x * LDS_STRIDE;

    int i = blockIdx.x * BLOCK + (int)threadIdx.x;
    float loss = 0.f;
    if (i < N)
        loss = pair_loss(pred + (size_t)i * 5, tgt + (size_t)i * 5,
                         wgt[i], myb);

    // ---- reduction: wave shuffle -> LDS -> one atomic per block ----
    #pragma unroll
    for (int off = 32; off > 0; off >>= 1)
        loss += __shfl_down(loss, off, 64);

    __shared__ float red[BLOCK / 64];
    int wave = threadIdx.x >> 6;
    int lane = threadIdx.x & 63;
    if (lane == 0) red[wave] = loss;
    __syncthreads();
    if (threadIdx.x == 0) {
        float s = 0.f;
        #pragma unroll
        for (int w = 0; w < BLOCK / 64; w++) s += red[w];
        atomicAdd(out, s * invN);
    }
}

extern "C" void kernel_launch(void* const* d_in, const int* in_sizes, int n_in,
                              void* d_out, int out_size, void* d_ws, size_t ws_size,
                              hipStream_t stream) {
    const float* pred = (const float*)d_in[0];
    const float* tgt  = (const float*)d_in[1];
    const float* wgt  = (const float*)d_in[2];
    float* out = (float*)d_out;
    int N = in_sizes[2];  // weight element count == N boxes

    hipMemsetAsync(out, 0, sizeof(float) * (size_t)out_size, stream);

    int grid = (N + BLOCK - 1) / BLOCK;
    obb_ciou_kernel<<<grid, BLOCK, 0, stream>>>(pred, tgt, wgt, out, N,
                                                1.f / (float)N);
}

// Round 4
// 128.630 us; speedup vs baseline: 1.0351x; 1.0092x over previous
//
#include <hip/hip_runtime.h>
#include <math.h>

// ---------------------------------------------------------------------------
// OBB CIoU loss, N independent box pairs -> scalar mean.
// R15: attack the pinned-39%-VALUBusy wall. Evidence: time tracks instr count
// at constant ~39% duty across 4 rounds; per-wave VALU issue interval ~17 cyc
// vs ~4-cyc dep latency; VGPR_Count=32 (compiler squeezed for occupancy we
// don't get -- measured ~3.3 waves/SIMD). Theory: register-starved codegen
// serializes the 16 independent vertex chains.
// Changes:
//  (a) __launch_bounds__(256,4): allow ~128 VGPR while guaranteeing >=4
//      waves/EU (>= today's measured residency) -> scheduler can interleave
//      independent chains.
//  (b) re-vectorize natural (x,y) chains as v2f -> v_pk_fma_f32 etc.
//      (frame transform, corners, du/dv, centroid, R=V-cen, hbb tail).
//  (c) shoelace: select-once sx/sy arrays then mul+fma ring (removes ~50
//      duplicated cndmasks).
// Carried from R14: box1-frame vertex generation with the reference's
// flipped-u quirk (u in (-1,0)), bf16 payload slab + packed-uint key Batcher
// sort + LDS gather, diamond pseudo-angle, native sin/cos, atan-identity
// v-term, frcp divides, exact-reference semantics.
// ---------------------------------------------------------------------------

#define BLOCK 256
#define NV 16
#define LDS_STRIDE 17   // 16 dword slots + 1 pad (odd stride -> free aliasing)

typedef float v2f __attribute__((ext_vector_type(2)));

// --- compile-time Batcher odd-even mergesort network for n=16 ---
struct CEList {
    int n;
    unsigned char lo[128];
    unsigned char hi[128];
};

constexpr CEList make_ces16() {
    CEList L{};
    L.n = 0;
    for (int p = 1; p < NV; p <<= 1)
        for (int k = p; k >= 1; k >>= 1)
            for (int j = k % p; j + k < NV; j += 2 * k)
                for (int i = 0; i < k; i++) {
                    int lo = i + j, hi = i + j + k;
                    if (hi < NV && (lo / (2 * p)) == (hi / (2 * p))) {
                        L.lo[L.n] = (unsigned char)lo;
                        L.hi[L.n] = (unsigned char)hi;
                        L.n++;
                    }
                }
    return L;
}

constexpr CEList CES = make_ces16();

__device__ __forceinline__ float frcp(float x) {
    return __builtin_amdgcn_rcpf(x);
}

__device__ __forceinline__ v2f splat2(float x) {
    v2f r; r.x = x; r.y = x; return r;
}

// (du,dv) = rotate e into box2's axis coords: du = e.cd + e.y sd paired form.
__device__ __forceinline__ v2f rot_ds(v2f e, float cd, float sd) {
    v2f sw; sw.x = e.y; sw.y = -e.x;
    return e * splat2(cd) + sw * splat2(sd);
}

// Diamond pseudo-angle, no wrap: range [0,4), a cyclic shift of atan2 order.
__device__ __forceinline__ float angle_key(float x, float y) {
    float ax = fabsf(x), ay = fabsf(y);
    float den = ax + ay;
    float r = x * frcp(den);
    r = (den > 0.f) ? r : 0.f;
    return (y >= 0.f) ? (1.f - r) : (3.f + r);
}

// Pack two floats to bf16x2 with round-to-nearest (payload only; keys exact).
__device__ __forceinline__ unsigned int pack_bf2(float x, float y) {
    unsigned int bx = __float_as_uint(x) + 0x8000u;
    unsigned int by = __float_as_uint(y) + 0x8000u;
    return (by & 0xFFFF0000u) | (bx >> 16);
}

// atan(z) for z in [0,1]: degree-11 odd minimax, max err ~1.5e-5 rad.
__device__ __forceinline__ float atan01(float z) {
    float z2 = z * z;
    float p = -0.01172120f;
    p = p * z2 + 0.05265332f;
    p = p * z2 - 0.11643287f;
    p = p * z2 + 0.19354346f;
    p = p * z2 - 0.33262347f;
    p = p * z2 + 0.99997726f;
    return z * p;
}

__device__ __forceinline__ float pair_loss(const float* __restrict__ p,
                                           const float* __restrict__ t,
                                           float wv,
                                           unsigned int* __restrict__ myb)
{
    const float MEPS = 1e-6f;           // MODE_EPS
    const float PIf  = 3.14159265358979323846f;
    const float TOLm = 1.f + 2e-6f;     // (1 + 2*tol) slab half-width scale

    float pcx = p[0], pcy = p[1], pw = p[2], ph = p[3], pa = p[4];
    float tcx = t[0], tcy = t[1], tw = t[2], th = t[3], ta = t[4];

    // |angles| bounded -> native sin/cos OK
    float ca = __cosf(pa), sa = __sinf(pa);
    float cb = __cosf(ta), sb = __sinf(ta);

    float hw1 = 0.5f * pw, hh1 = 0.5f * ph;
    float hw2 = 0.5f * tw, hh2 = 0.5f * th;

    // ---- box2 in box1's axis frame (packed) ----
    float ddx = tcx - pcx, ddy = tcy - pcy;
    v2f dd;  dd.x = ddx;  dd.y = ddy;
    v2f dds; dds.x = ddy; dds.y = -ddx;
    v2f c2 = dd * splat2(ca) + dds * splat2(sa);   // (c2x, c2y)
    float cd  = cb * ca + sb * sa;      // cos(ta - pa)
    float sd  = sb * ca - cb * sa;      // sin(ta - pa)

    // box2 half-axes: A = hw2*(cd,sd), B = hh2*(-sd,cd)
    v2f axd2; axd2.x = cd;  axd2.y = sd;
    v2f bxd2; bxd2.x = -sd; bxd2.y = cd;
    v2f A = splat2(hw2) * axd2;
    v2f B = splat2(hh2) * bxd2;
    v2f qpA = c2 + A, qmA = c2 - A;
    // reference corner ring: C0 = q+A-B, C1 = q-A-B, C2 = q-A+B, C3 = q+A+B
    v2f C0 = qpA - B, C1 = qmA - B, C2c = qmA + B, C3 = qpA + B;

    v2f  V[NV];
    bool msk[NV];

    // ---- corners1 (= (+-hw1,+-hh1), ring order) inside box2 -> slots 0..3
    // reference p_ab/p_ad window == |du|<hw2*(1+2tol) && |dv|<hh2*(1+2tol)
    {
        float exl = -hw1 - c2.x, exh = hw1 - c2.x;
        float eyl = -hh1 - c2.y, eyh = hh1 - c2.y;
        float lw2 = hw2 * TOLm, lh2 = hh2 * TOLm;
        v2f e, duv;
        e.x = exh; e.y = eyl; duv = rot_ds(e, cd, sd);        // K0=( hw1,-hh1)
        msk[0] = (fabsf(duv.x) < lw2) && (fabsf(duv.y) < lh2);
        V[0].x = hw1;  V[0].y = -hh1;
        e.x = exl; e.y = eyl; duv = rot_ds(e, cd, sd);        // K1=(-hw1,-hh1)
        msk[1] = (fabsf(duv.x) < lw2) && (fabsf(duv.y) < lh2);
        V[1].x = -hw1; V[1].y = -hh1;
        e.x = exl; e.y = eyh; duv = rot_ds(e, cd, sd);        // K2=(-hw1, hh1)
        msk[2] = (fabsf(duv.x) < lw2) && (fabsf(duv.y) < lh2);
        V[2].x = -hw1; V[2].y = hh1;
        e.x = exh; e.y = eyh; duv = rot_ds(e, cd, sd);        // K3=( hw1, hh1)
        msk[3] = (fabsf(duv.x) < lw2) && (fabsf(duv.y) < lh2);
        V[3].x = hw1;  V[3].y = hh1;
    }

    // ---- corners2 inside box1 (axis-aligned slab) -> slots 4..7
    {
        float lw1 = hw1 * TOLm, lh1 = hh1 * TOLm;
        msk[4] = (fabsf(C0.x) < lw1) && (fabsf(C0.y) < lh1);  V[4] = C0;
        msk[5] = (fabsf(C1.x) < lw1) && (fabsf(C1.y) < lh1);  V[5] = C1;
        msk[6] = (fabsf(C2c.x) < lw1) && (fabsf(C2c.y) < lh1); V[6] = C2c;
        msk[7] = (fabsf(C3.x) < lw1) && (fabsf(C3.y) < lh1);  V[7] = C3;
    }

    // ---- quirky edge crossings -> slots 8..15 (2 per box1 edge) ----
    // box2 edge j: start S_j = C_j, dir D_j: D0=-2A, D1=+2B, D2=+2A, D3=-2B
    {
        float twcd = A.x + A.x, twsd = A.y + A.y;          // 2A
        float thsd = -(B.x + B.x), thcd = B.y + B.y;       // 2B = (-thsd, thcd)
        float rax = frcp(twcd), ray = frcp(twsd);
        float rbx = frcp(thsd), rby = frcp(thcd);

        float Sx[4]  = { C0.x, C1.x, C2c.x, C3.x };
        float Sy[4]  = { C0.y, C1.y, C2c.y, C3.y };
        float Dxe[4] = { -twcd, -thsd, twcd, thsd };
        float Dye[4] = { -twsd, thcd, twsd, -thcd };
        float iDx[4] = { -rax, -rbx, rax, rbx };
        float iDy[4] = { -ray, rby, ray, -rby };

        #pragma unroll
        for (int e1 = 0; e1 < 4; e1++) {
            // box1 ring: e0 bottom(y=-hh1), e1 left(x=-hw1),
            //            e2 top(y=+hh1),   e3 right(x=+hw1)
            const bool horiz = (e1 == 0) || (e1 == 2);
            const float cc   = (e1 == 0) ? -hh1 : (e1 == 1) ? -hw1
                             : (e1 == 2) ?  hh1 :  hw1;
            const float lim  = horiz ? hw1 : hh1;
            float q[4]; bool qm[4];
            #pragma unroll
            for (int j = 0; j < 4; j++) {
                float u = horiz ? (cc - Sy[j]) * iDy[j]
                                : (cc - Sx[j]) * iDx[j];
                float w = horiz ? fmaf(u, Dxe[j], Sx[j])
                                : fmaf(u, Dye[j], Sy[j]);
                // u in (-1,0): frame-exact image of reference's flipped-u
                // mask; |w|<lim == t in (0,1); parallel -> inf/NaN -> reject.
                qm[j] = (u > -1.f) && (u < 0.f) && (fabsf(w) < lim);
                q[j] = w;
            }
            bool mfL = qm[0] || qm[1];
            float fL = qm[0] ? q[0] : q[1];
            bool msL = qm[0] && qm[1];
            bool mfR = qm[2] || qm[3];
            float fR = qm[2] ? q[2] : q[3];
            bool msR = qm[2] && qm[3];
            int s0 = 8 + 2 * e1, s1 = s0 + 1;
            float w0 = mfL ? fL : fR;
            msk[s0]  = mfL || mfR;
            float t2v = msL ? q[1] : fR;
            float w1 = mfL ? t2v : q[3];
            msk[s1]  = msL || (mfL && mfR) || msR;
            if (horiz) { V[s0].x = w0; V[s0].y = cc; V[s1].x = w1; V[s1].y = cc; }
            else       { V[s0].x = cc; V[s0].y = w0; V[s1].x = cc; V[s1].y = w1; }
        }
    }

    // ---- centroid of valid verts (packed adds) ----
    v2f s2 = splat2(0.f);
    float cnt = 0.f;
    const v2f Z2 = splat2(0.f);
    #pragma unroll
    for (int k = 0; k < NV; k++) {
        s2  += msk[k] ? V[k] : Z2;
        cnt += msk[k] ? 1.f : 0.f;
    }
    float rden = frcp(fmaxf(cnt, 1.f));
    v2f cen = s2 * splat2(rden);

    // ---- relative coords -> LDS scatter (bf16x2) + packed key (key|slot) ----
    unsigned int ku[NV];
    #pragma unroll
    for (int k = 0; k < NV; k++) {
        v2f R = V[k] - cen;
        myb[k] = pack_bf2(R.x, R.y);
        float a = msk[k] ? angle_key(R.x, R.y) : 1e7f;  // key from FULL floats
        ku[k] = (__float_as_uint(a) & 0xFFFFFFF0u) | (unsigned int)k;
    }

    // ---- sort 16 packed keys (Batcher network, 2 VALU per CE) ----
    #pragma unroll
    for (int c = 0; c < CES.n; c++) {
        const int lo = CES.lo[c], hi = CES.hi[c];
        unsigned int a = ku[lo], b = ku[hi];
        ku[lo] = a < b ? a : b;
        ku[hi] = a < b ? b : a;
    }

    // ---- gather payload by sorted index; select-once; shoelace ring ----
    const unsigned int VALID_LIM = 0x49742400u;  // bits of 1e6f
    float gx[NV], gy[NV];
    bool  gv[NV];
    #pragma unroll
    for (int k = 0; k < NV; k++) {
        unsigned int pk = myb[ku[k] & 15u];
        gx[k] = __uint_as_float(pk << 16);
        gy[k] = __uint_as_float(pk & 0xFFFF0000u);
        gv[k] = ku[k] < VALID_LIM;
    }
    float fx = gx[0], fy = gy[0];
    float sx[NV], sy[NV];
    #pragma unroll
    for (int k = 0; k < NV; k++) {
        sx[k] = gv[k] ? gx[k] : fx;
        sy[k] = gv[k] ? gy[k] : fy;
    }
    float cross = 0.f;
    #pragma unroll
    for (int k = 0; k < NV; k++) {
        int kn = (k + 1) & (NV - 1);     // constant after unroll
        cross += sx[k] * sy[kn] - sy[k] * sx[kn];
    }
    float inter = fabsf(cross) * 0.5f;

    // ---- CIoU (hbb tail packed) ----
    float area1 = pw * ph, area2 = tw * th;
    float iou = inter * frcp(area1 + area2 - inter);
    iou = fminf(fmaxf(iou, 0.f), 1.f);

    float cA = fabsf(ca), sA = fabsf(sa);
    float cB = fabsf(cb), sB = fabsf(sb);
    v2f csA; csA.x = cA; csA.y = sA;
    v2f scA; scA.x = sA; scA.y = cA;
    v2f csB; csB.x = cB; csB.y = sB;
    v2f scB; scB.x = sB; scB.y = cB;
    v2f dwh1 = (splat2(pw) * csA + splat2(ph) * scA) * splat2(0.5f);
    v2f dwh2 = (splat2(tw) * csB + splat2(th) * scB) * splat2(0.5f);
    v2f cp; cp.x = pcx; cp.y = pcy;
    v2f ct; ct.x = tcx; ct.y = tcy;
    v2f plo = cp - dwh1, phi = cp + dwh1;
    v2f tlo = ct - dwh2, thi = ct + dwh2;

    v2f hi = __builtin_elementwise_max(phi, thi);
    v2f lo = __builtin_elementwise_min(plo, tlo);
    v2f en = __builtin_elementwise_max(hi - lo, splat2(0.f));
    float c2v = en.x * en.x + en.y * en.y + MEPS;
    float rho2 = ddx * ddx + ddy * ddy;

    // v-term: atan(r1) - atan(r2) = atan((r1-r2)/(1+r1*r2)), exact for
    // r1*r2 > 0 (both aspect ratios positive). dv is squared -> sign-free.
    float factor = 4.f / (PIf * PIf);
    float r1 = tw * frcp(th + MEPS);
    float r2 = pw * frcp(ph + MEPS);
    float xd = (r1 - r2) * frcp(1.f + r1 * r2);
    float axd = fabsf(xd);
    bool  big = axd > 1.f;
    float z   = big ? frcp(axd) : axd;
    float at  = atan01(z);
    float dv  = big ? ((0.5f * PIf) - at) : at;   // |atan(xd)|
    float v_ = factor * dv * dv;
    float alpha = (iou > 0.5f) ? v_ * frcp(1.f - iou + v_ + MEPS) : 0.f;

    float rhoterm = fminf(fmaxf(rho2 * frcp(c2v), 0.f), 1.f);
    float ciou = iou - (rhoterm + alpha * v_);
    return (1.f - ciou) * wv;
}

__global__ __launch_bounds__(BLOCK, 4)
void obb_ciou_kernel(const float* __restrict__ pred,
                     const float* __restrict__ tgt,
                     const float* __restrict__ wgt,
                     float* __restrict__ out,
                     int N, float invN)
{
    __shared__ unsigned int slab[BLOCK * LDS_STRIDE];
    unsigned int* myb = slab + (int)threadIdx.x * LDS_STRIDE;

    int i = blockIdx.x * BLOCK + (int)threadIdx.x;
    float loss = 0.f;
    if (i < N)
        loss = pair_loss(pred + (size_t)i * 5, tgt + (size_t)i * 5,
                         wgt[i], myb);

    // ---- reduction: wave shuffle -> LDS -> one atomic per block ----
    #pragma unroll
    for (int off = 32; off > 0; off >>= 1)
        loss += __shfl_down(loss, off, 64);

    __shared__ float red[BLOCK / 64];
    int wave = threadIdx.x >> 6;
    int lane = threadIdx.x & 63;
    if (lane == 0) red[wave] = loss;
    __syncthreads();
    if (threadIdx.x == 0) {
        float s = 0.f;
        #pragma unroll
        for (int w = 0; w < BLOCK / 64; w++) s += red[w];
        atomicAdd(out, s * invN);
    }
}

extern "C" void kernel_launch(void* const* d_in, const int* in_sizes, int n_in,
                              void* d_out, int out_size, void* d_ws, size_t ws_size,
                              hipStream_t stream) {
    const float* pred = (const float*)d_in[0];
    const float* tgt  = (const float*)d_in[1];
    const float* wgt  = (const float*)d_in[2];
    float* out = (float*)d_out;
    int N = in_sizes[2];  // weight element count == N boxes

    hipMemsetAsync(out, 0, sizeof(float) * (size_t)out_size, stream);

    int grid = (N + BLOCK - 1) / BLOCK;
    obb_ciou_kernel<<<grid, BLOCK, 0, stream>>>(pred, tgt, wgt, out, N,
                                                1.f / (float)N);
}